// Round 1
// baseline (379.825 us; speedup 1.0000x reference)
//
#include <hip/hip_runtime.h>
#include <hip/hip_bf16.h>
#include <math.h>

// Problem dims (fixed by the reference)
#define M_DIM 16384
#define N_DIM 2048
#define K_DIM 2048
#define BM 128
#define BN 128
#define BK 64   // 8 groups of 8 bf16 (16B) per row

typedef __attribute__((ext_vector_type(8))) short bf16x8;        // MFMA A/B operand (4 VGPRs)
typedef __attribute__((ext_vector_type(4))) float f32x4;         // MFMA C/D
typedef __attribute__((ext_vector_type(8))) unsigned short us8;  // 16B vector store

typedef __attribute__((address_space(1))) const unsigned short global_us;
typedef __attribute__((address_space(3))) unsigned short lds_us;

__device__ __forceinline__ unsigned short f2bf_rn(float f) {
  union { float f; unsigned int u; } v; v.f = f;
  unsigned int u = v.u;
  return (unsigned short)((u + 0x7fffu + ((u >> 16) & 1u)) >> 16);  // RNE, no NaN inputs
}

// ---------- pre-pass 1: x_scaled = sign(x)*|x|^a, cast to bf16 ----------
__global__ __launch_bounds__(256) void scale_x_kernel(const float* __restrict__ x,
                                                      const float* __restrict__ alpha,
                                                      unsigned short* __restrict__ out) {
  const float a = alpha[0];
  const size_t base = ((size_t)blockIdx.x * 256u + threadIdx.x) * 8u;
  const float4* xp = (const float4*)(x + base);
  float4 v0 = xp[0];
  float4 v1 = xp[1];
  float s[8] = {v0.x, v0.y, v0.z, v0.w, v1.x, v1.y, v1.z, v1.w};
  us8 r;
  if (a == 0.5f) {  // uniform branch; setup uses a = 0.5 exactly
#pragma unroll
    for (int i = 0; i < 8; ++i)
      r[i] = f2bf_rn(copysignf(sqrtf(fabsf(s[i])), s[i]));
  } else {
#pragma unroll
    for (int i = 0; i < 8; ++i)
      r[i] = f2bf_rn(copysignf(powf(fabsf(s[i]), a), s[i]));
  }
  *(us8*)(out + base) = r;
}

// ---------- pre-pass 2: W[o,i] = centroids[W_q[o,i]] as bf16 [N][K] ----------
__global__ __launch_bounds__(256) void dequant_w_kernel(const int* __restrict__ Wq,
                                                        const float* __restrict__ cent,
                                                        unsigned short* __restrict__ out) {
  __shared__ unsigned short cb[16];
  if (threadIdx.x < 16) cb[threadIdx.x] = f2bf_rn(cent[threadIdx.x]);
  __syncthreads();
  const size_t base = ((size_t)blockIdx.x * 256u + threadIdx.x) * 8u;
  const int4* qp = (const int4*)(Wq + base);
  int4 q0 = qp[0], q1 = qp[1];
  us8 r;
  r[0] = cb[q0.x]; r[1] = cb[q0.y]; r[2] = cb[q0.z]; r[3] = cb[q0.w];
  r[4] = cb[q1.x]; r[5] = cb[q1.y]; r[6] = cb[q1.z]; r[7] = cb[q1.w];
  *(us8*)(out + base) = r;
}

// ---------- GEMM: C[m][n] = sum_k A[m][k]*B[n][k], epilogue sign*|v|^(1/a) ----------
// m97 structure: 128x128 tile, BK=64, 4 waves (2x2), 4x4 frags of 16x16x32 bf16.
// LDS k-groups XOR-swizzled (phys = logical ^ (row&7)) via the staging GLOBAL
// address (LDS side must remain base + lane*16 — global_load_lds constraint).
__global__ __launch_bounds__(256) void gemm_bt_kernel(const unsigned short* __restrict__ A,
                                                      const unsigned short* __restrict__ B,
                                                      float* __restrict__ C,
                                                      const float* __restrict__ alpha) {
  __shared__ unsigned short As[BM * BK];  // 16 KB
  __shared__ unsigned short Bs[BN * BK];  // 16 KB

  const int tid  = threadIdx.x;
  const int wave = tid >> 6;
  const int lane = tid & 63;

  // 16x16 super-tile block swizzle: ~16 MB footprint per 256-block batch
  const int bid    = blockIdx.x;          // 0..2047
  const int st     = bid >> 8;            // 0..7
  const int within = bid & 255;
  const int bm = st * 16 + (within & 15);
  const int bn = within >> 4;
  const int m0 = bm * BM;
  const int n0 = bn * BN;

  const int wm   = wave >> 1;             // 0..1
  const int wn   = wave & 1;              // 0..1
  const int r    = lane & 15;
  const int quad = lane >> 4;             // 0..3

  // staging: inst j covers rows j*32 + wave*8 + lane/8; lane writes LDS base + lane*16
  const int srow = wave * 8 + (lane >> 3);
  const int sg   = (lane & 7) ^ (lane >> 3);   // logical k-group this lane fetches (swizzle)
  const unsigned short* aBase = A + (size_t)(m0 + srow) * K_DIM + sg * 8;
  const unsigned short* bBase = B + (size_t)(n0 + srow) * K_DIM + sg * 8;

  f32x4 acc[4][4];
#pragma unroll
  for (int i = 0; i < 4; ++i)
#pragma unroll
    for (int j = 0; j < 4; ++j)
      acc[i][j] = f32x4{0.f, 0.f, 0.f, 0.f};

  for (int kt = 0; kt < K_DIM / BK; ++kt) {
    const int k0 = kt * BK;
#pragma unroll
    for (int j = 0; j < 4; ++j) {
      __builtin_amdgcn_global_load_lds(
          (global_us*)(aBase + (size_t)j * 32 * K_DIM + k0),
          (lds_us*)&As[(j * 32 + wave * 8) * BK], 16, 0, 0);
    }
#pragma unroll
    for (int j = 0; j < 4; ++j) {
      __builtin_amdgcn_global_load_lds(
          (global_us*)(bBase + (size_t)j * 32 * K_DIM + k0),
          (lds_us*)&Bs[(j * 32 + wave * 8) * BK], 16, 0, 0);
    }
    __syncthreads();  // drains vmcnt -> LDS tiles valid

#pragma unroll
    for (int kk = 0; kk < 2; ++kk) {
      bf16x8 af[4], bq[4];
#pragma unroll
      for (int f = 0; f < 4; ++f) {
        const int pa = ((kk * 4 + quad) ^ (r & 7)) * 8;  // swizzled phys group
        const int ml = wm * 64 + f * 16 + r;             // ml&7 == r&7
        af[f] = *(const bf16x8*)&As[ml * BK + pa];
        const int nl = wn * 64 + f * 16 + r;
        bq[f] = *(const bf16x8*)&Bs[nl * BK + pa];
      }
#pragma unroll
      for (int mf = 0; mf < 4; ++mf)
#pragma unroll
        for (int nf = 0; nf < 4; ++nf)
          acc[mf][nf] = __builtin_amdgcn_mfma_f32_16x16x32_bf16(af[mf], bq[nf], acc[mf][nf], 0, 0, 0);
    }
    __syncthreads();  // all waves done reading before next stage overwrites
  }

  // epilogue: signed pow(v, 1/a); a==0.5 -> v*|v|
  const float a = alpha[0];
  const bool simple = (a == 0.5f);
  const float inv_a = 1.0f / a;
#pragma unroll
  for (int mf = 0; mf < 4; ++mf) {
#pragma unroll
    for (int nf = 0; nf < 4; ++nf) {
      // C/D layout (m89/m91): col = lane&15, row = quad*4 + reg
      const int gm = m0 + wm * 64 + mf * 16 + quad * 4;
      const int gn = n0 + wn * 64 + nf * 16 + r;
      float* cp = C + (size_t)gm * N_DIM + gn;
#pragma unroll
      for (int v = 0; v < 4; ++v) {
        float t = acc[mf][nf][v];
        cp[(size_t)v * N_DIM] = simple ? t * fabsf(t)
                                       : copysignf(powf(fabsf(t), inv_a), t);
      }
    }
  }
}

extern "C" void kernel_launch(void* const* d_in, const int* in_sizes, int n_in,
                              void* d_out, int out_size, void* d_ws, size_t ws_size,
                              hipStream_t stream) {
  const float* x     = (const float*)d_in[0];  // [16384, 2048] fp32
  const float* cent  = (const float*)d_in[1];  // [16] fp32
  const float* alpha = (const float*)d_in[2];  // [1] fp32
  const int*   Wq    = (const int*)d_in[3];    // [2048, 2048] int32
  float* out = (float*)d_out;                  // [16384, 2048] fp32

  // workspace: x_scaled bf16 [M][K] (64 MiB) then W bf16 [N][K] (8 MiB)
  unsigned short* Axs = (unsigned short*)d_ws;
  unsigned short* Wb  = (unsigned short*)((char*)d_ws + (size_t)M_DIM * K_DIM * 2);

  scale_x_kernel<<<(M_DIM * (size_t)K_DIM) / (256 * 8), 256, 0, stream>>>(x, alpha, Axs);
  dequant_w_kernel<<<(N_DIM * (size_t)K_DIM) / (256 * 8), 256, 0, stream>>>(Wq, cent, Wb);

  dim3 grid((M_DIM / BM) * (N_DIM / BN));  // 2048 blocks
  gemm_bt_kernel<<<grid, 256, 0, stream>>>(Axs, Wb, out, alpha);
}

// Round 2
// 320.183 us; speedup vs baseline: 1.1863x; 1.1863x over previous
//
#include <hip/hip_runtime.h>
#include <hip/hip_bf16.h>
#include <math.h>

// Problem dims (fixed by the reference)
#define M_DIM 16384
#define N_DIM 2048
#define K_DIM 2048
#define BM 128
#define BN 128
#define BKB 128  // K-tile in BYTES (128 int8) -> same 128B/row, 16KB tiles as m97 bf16

typedef __attribute__((ext_vector_type(4))) int i32x4;    // MFMA i8 A/B (16 int8) and C/D
typedef __attribute__((ext_vector_type(8))) char char8;   // 8B int8 store

typedef __attribute__((address_space(1))) const unsigned char global_u8;
typedef __attribute__((address_space(3))) unsigned char lds_u8;

// ---------- pre-pass 1: per-row signed-pow + int8 quantize ----------
// One block per row of x. v = sign(x)*|x|^a; s_a[row] = rowmax/127; q = rint(v/s).
__global__ __launch_bounds__(256) void quant_x_kernel(const float* __restrict__ x,
                                                      const float* __restrict__ alpha,
                                                      char* __restrict__ xq,
                                                      float* __restrict__ s_a) {
  __shared__ float wmax[4];
  const int row = blockIdx.x;
  const int tid = threadIdx.x;
  const size_t base = (size_t)row * K_DIM + tid * 8;
  const float a = alpha[0];
  const float4* xp = (const float4*)(x + base);
  float4 v0 = xp[0];
  float4 v1 = xp[1];
  float v[8] = {v0.x, v0.y, v0.z, v0.w, v1.x, v1.y, v1.z, v1.w};
  if (a == 0.5f) {  // uniform branch; setup uses a = 0.5 exactly
#pragma unroll
    for (int i = 0; i < 8; ++i) v[i] = copysignf(sqrtf(fabsf(v[i])), v[i]);
  } else {
#pragma unroll
    for (int i = 0; i < 8; ++i) v[i] = copysignf(powf(fabsf(v[i]), a), v[i]);
  }
  float m = 0.f;
#pragma unroll
  for (int i = 0; i < 8; ++i) m = fmaxf(m, fabsf(v[i]));
  // wave64 reduce, then cross-wave via LDS
#pragma unroll
  for (int off = 32; off > 0; off >>= 1) m = fmaxf(m, __shfl_down(m, off));
  if ((tid & 63) == 0) wmax[tid >> 6] = m;
  __syncthreads();
  float rowmax = fmaxf(fmaxf(wmax[0], wmax[1]), fmaxf(wmax[2], wmax[3]));
  float inv, s;
  if (rowmax > 0.f) { inv = 127.0f / rowmax; s = rowmax * (1.0f / 127.0f); }
  else { inv = 0.f; s = 0.f; }
  char8 q;
#pragma unroll
  for (int i = 0; i < 8; ++i) {
    int qi = (int)__builtin_rintf(v[i] * inv);
    qi = qi > 127 ? 127 : (qi < -127 ? -127 : qi);
    q[i] = (char)qi;
  }
  *(char8*)(xq + base) = q;
  if (tid == 0) s_a[row] = s;
}

// ---------- pre-pass 2: codebook gather -> int8, per-tensor scale ----------
__global__ __launch_bounds__(256) void quant_w_kernel(const int* __restrict__ Wq,
                                                      const float* __restrict__ cent,
                                                      char* __restrict__ wq8,
                                                      float* __restrict__ s_w) {
  __shared__ char cb[16];
  const int tid = threadIdx.x;
  float cmax = 0.f;
#pragma unroll
  for (int j = 0; j < 16; ++j) cmax = fmaxf(cmax, fabsf(cent[j]));
  const float invw = 127.0f / cmax;
  if (tid < 16) cb[tid] = (char)__builtin_rintf(cent[tid] * invw);
  __syncthreads();
  const size_t base = ((size_t)blockIdx.x * 256u + tid) * 8u;
  const int4* qp = (const int4*)(Wq + base);
  int4 q0 = qp[0], q1 = qp[1];
  char8 r;
  r[0] = cb[q0.x]; r[1] = cb[q0.y]; r[2] = cb[q0.z]; r[3] = cb[q0.w];
  r[4] = cb[q1.x]; r[5] = cb[q1.y]; r[6] = cb[q1.z]; r[7] = cb[q1.w];
  *(char8*)(wq8 + base) = r;
  if (blockIdx.x == 0 && tid == 0) s_w[0] = cmax * (1.0f / 127.0f);
}

// ---------- GEMM: int8 m97 structure. C[m][n] = s_a[m]*s_w * idot, epilogue sign-pow ----------
// BK=128 int8 = 128 B/row: identical staging/swizzle byte pattern to the bf16 m97 kernel,
// but 16 K-iterations instead of 32 and K=64 per MFMA (mfma_i32_16x16x64_i8, exact int32 acc).
__global__ __launch_bounds__(256) void gemm_i8_kernel(const unsigned char* __restrict__ A,
                                                      const unsigned char* __restrict__ B,
                                                      float* __restrict__ C,
                                                      const float* __restrict__ alpha,
                                                      const float* __restrict__ s_a,
                                                      const float* __restrict__ s_w) {
  __shared__ unsigned char As[BM * BKB];  // 16 KB
  __shared__ unsigned char Bs[BN * BKB];  // 16 KB

  const int tid  = threadIdx.x;
  const int wave = tid >> 6;
  const int lane = tid & 63;

  // 16x16 super-tile block swizzle (L2 locality)
  const int bid    = blockIdx.x;          // 0..2047
  const int st     = bid >> 8;
  const int within = bid & 255;
  const int m0 = (st * 16 + (within & 15)) * BM;
  const int n0 = (within >> 4) * BN;

  const int wm   = wave >> 1;
  const int wn   = wave & 1;
  const int r    = lane & 15;
  const int quad = lane >> 4;

  // staging: rows j*32 + wave*8 + lane/8; LDS dest = uniform base + lane*16 (HW rule)
  const int srow = wave * 8 + (lane >> 3);
  const int sg   = (lane & 7) ^ (lane >> 3);  // logical 16B k-group (XOR swizzle)
  const unsigned char* aBase = A + (size_t)(m0 + srow) * K_DIM + sg * 16;
  const unsigned char* bBase = B + (size_t)(n0 + srow) * K_DIM + sg * 16;

  i32x4 acc[4][4];
#pragma unroll
  for (int i = 0; i < 4; ++i)
#pragma unroll
    for (int j = 0; j < 4; ++j)
      acc[i][j] = i32x4{0, 0, 0, 0};

  for (int kt = 0; kt < K_DIM / BKB; ++kt) {  // 16 iterations
    const int k0 = kt * BKB;
#pragma unroll
    for (int j = 0; j < 4; ++j) {
      __builtin_amdgcn_global_load_lds(
          (global_u8*)(aBase + (size_t)j * 32 * K_DIM + k0),
          (lds_u8*)&As[(j * 32 + wave * 8) * BKB], 16, 0, 0);
    }
#pragma unroll
    for (int j = 0; j < 4; ++j) {
      __builtin_amdgcn_global_load_lds(
          (global_u8*)(bBase + (size_t)j * 32 * K_DIM + k0),
          (lds_u8*)&Bs[(j * 32 + wave * 8) * BKB], 16, 0, 0);
    }
    __syncthreads();

#pragma unroll
    for (int kk = 0; kk < 2; ++kk) {
      i32x4 af[4], bq[4];
#pragma unroll
      for (int f = 0; f < 4; ++f) {
        const int pa = ((kk * 4 + quad) ^ (r & 7)) * 16;  // swizzled phys 16B group
        const int ml = wm * 64 + f * 16 + r;              // ml&7 == r&7
        af[f] = *(const i32x4*)&As[ml * BKB + pa];
        const int nl = wn * 64 + f * 16 + r;
        bq[f] = *(const i32x4*)&Bs[nl * BKB + pa];
      }
#pragma unroll
      for (int mf = 0; mf < 4; ++mf)
#pragma unroll
        for (int nf = 0; nf < 4; ++nf)
          acc[mf][nf] = __builtin_amdgcn_mfma_i32_16x16x64_i8(af[mf], bq[nf], acc[mf][nf], 0, 0, 0);
    }
    __syncthreads();
  }

  // epilogue: t = s_a[row]*s_w*idot; out = sign(t)*|t|^(1/a); a==0.5 -> t*|t|
  const float a = alpha[0];
  const bool simple = (a == 0.5f);
  const float inv_a = 1.0f / a;
  const float sw = s_w[0];
#pragma unroll
  for (int mf = 0; mf < 4; ++mf) {
    const int gmb = m0 + wm * 64 + mf * 16 + quad * 4;
    float sa[4];
#pragma unroll
    for (int v = 0; v < 4; ++v) sa[v] = s_a[gmb + v] * sw;
#pragma unroll
    for (int nf = 0; nf < 4; ++nf) {
      const int gn = n0 + wn * 64 + nf * 16 + r;
      float* cp = C + (size_t)gmb * N_DIM + gn;
#pragma unroll
      for (int v = 0; v < 4; ++v) {
        float t = (float)acc[mf][nf][v] * sa[v];
        cp[(size_t)v * N_DIM] = simple ? t * fabsf(t)
                                       : copysignf(powf(fabsf(t), inv_a), t);
      }
    }
  }
}

extern "C" void kernel_launch(void* const* d_in, const int* in_sizes, int n_in,
                              void* d_out, int out_size, void* d_ws, size_t ws_size,
                              hipStream_t stream) {
  const float* x     = (const float*)d_in[0];  // [16384, 2048] fp32
  const float* cent  = (const float*)d_in[1];  // [16] fp32
  const float* alpha = (const float*)d_in[2];  // [1] fp32
  const int*   Wq    = (const int*)d_in[3];    // [2048, 2048] int32
  float* out = (float*)d_out;                  // [16384, 2048] fp32

  // ws layout: xq int8 [M][K] (32 MiB) | wq8 int8 [N][K] (4 MiB) | s_a [M] f32 | s_w [1] f32
  char*  xq  = (char*)d_ws;
  char*  wq8 = xq + (size_t)M_DIM * K_DIM;
  float* s_a = (float*)(wq8 + (size_t)N_DIM * K_DIM);
  float* s_w = s_a + M_DIM;

  quant_x_kernel<<<M_DIM, 256, 0, stream>>>(x, alpha, xq, s_a);
  quant_w_kernel<<<(N_DIM * (size_t)K_DIM) / (256 * 8), 256, 0, stream>>>(Wq, cent, wq8, s_w);

  dim3 grid((M_DIM / BM) * (N_DIM / BN));  // 2048 blocks
  gemm_i8_kernel<<<grid, 256, 0, stream>>>((const unsigned char*)xq, (const unsigned char*)wq8,
                                           out, alpha, s_a, s_w);
}